// Round 2
// baseline (450.372 us; speedup 1.0000x reference)
//
#include <hip/hip_runtime.h>
#include <hip/hip_bf16.h>
#include <stdint.h>

// Problem constants: B=16, XL=YL=D=1024
#define NBATCH 16
#define NDIM   1024
#define NEL    (16u*1024u*1024u)   // elements per [B,1024,1024] tensor

typedef __attribute__((ext_vector_type(8))) short bf16x8;
typedef __attribute__((ext_vector_type(4))) short short4_t;
typedef __attribute__((ext_vector_type(4))) float f32x4;
typedef __attribute__((ext_vector_type(4))) int   i32x4;

__device__ __forceinline__ short f2bf(float f){
  union { __hip_bfloat16 b; short s; } u;
  u.b = __float2bfloat16(f);   // RNE
  return u.s;
}
__device__ __forceinline__ float bf2f(short s){
  union { short s; __hip_bfloat16 b; } u;
  u.s = s;
  return __bfloat162float(u.b);
}

// -------- kernel 1: f32 -> bf16 hi + bf16 lo (split for 3-MFMA fp32 emulation)
__global__ __launch_bounds__(256) void k_split(const float* __restrict__ in,
                                               short* __restrict__ hi,
                                               short* __restrict__ lo)
{
  const size_t i = ((size_t)blockIdx.x * 256 + threadIdx.x) * 4;
  f32x4 v = *(const f32x4*)(in + i);
  short4_t h, l;
  #pragma unroll
  for (int j = 0; j < 4; j++){
    short hb = f2bf(v[j]);
    h[j] = hb;
    l[j] = f2bf(v[j] - bf2f(hb));
  }
  *(short4_t*)(hi + i) = h;
  *(short4_t*)(lo + i) = l;
}

// -------- kernel 2: ys [b][y][d] f32 -> ysT [b][d][y] bf16 (hi only; GEMM2 is plain bf16)
__global__ __launch_bounds__(256) void k_transpose(const float* __restrict__ ys,
                                                   short* __restrict__ ysT)
{
  __shared__ float t[32][33];
  const int b = blockIdx.z;
  const int y0 = blockIdx.y * 32;
  const int d0 = blockIdx.x * 32;
  const float* src = ys + ((size_t)b * NDIM + y0) * NDIM + d0;
  #pragma unroll
  for (int r = threadIdx.y; r < 32; r += 8)
    t[r][threadIdx.x] = src[(size_t)r * NDIM + threadIdx.x];
  __syncthreads();
  short* dst = ysT + ((size_t)b * NDIM + d0) * NDIM + y0;
  #pragma unroll
  for (int r = threadIdx.y; r < 32; r += 8)
    dst[(size_t)r * NDIM + threadIdx.x] = f2bf(t[threadIdx.x][r]);
}

// -------- global->LDS direct copy, 16B per lane (dst must be wave-uniform; HW adds lane*16)
__device__ __forceinline__ void gload_lds16(const short* g, short* l){
  __builtin_amdgcn_global_load_lds((const __attribute__((address_space(1))) void*)g,
                                   (__attribute__((address_space(3))) void*)l,
                                   16, 0, 0);
}

// -------- GEMM  C[b] = A[b] (MxK row-major) * B[b]^T (B is NxK row-major), M=N=K=1024
// SPLIT=1: A,B given as hi+lo bf16 pairs, 3 MFMAs (hi*hi + hi*lo + lo*hi)  -> ~fp32 scores
// SPLIT=0: plain bf16 (hi only)
// 128x128 tile, BK=32, 256 threads = 4 waves in 2x2, each wave 64x64 out (4x4 16x16 frags).
// LDS tiles [128][32] bf16, k-slots (8 bf16 = 16B) XOR-swizzled: phys_slot = slot ^ ((row>>1)&3)
// -> ds_read_b128 fragment reads hit the 8-cycle b128 floor (8 lanes / 4-bank group, distinct
// addrs). global_load_lds writes linearly, so the *global* source is pre-swizzled (rule 21).
template<int SPLIT>
__global__ __launch_bounds__(256, 2) void k_gemm_bt(
    const short* __restrict__ Ahi, const short* __restrict__ Alo,
    const short* __restrict__ Bhi, const short* __restrict__ Blo,
    float* __restrict__ C)
{
  constexpr int NT = SPLIT ? 4 : 2;     // tiles: Ahi,[Alo],Bhi,[Blo]
  constexpr int TB = SPLIT ? 2 : 1;     // index of Bhi tile
  __shared__ __align__(16) short lds[2][NT][128 * 32];

  const int tid  = threadIdx.x;
  const int lane = tid & 63;
  const int wid  = tid >> 6;
  const int wr   = wid >> 1;
  const int wc   = wid & 1;

  const size_t bofs = (size_t)blockIdx.z * NDIM * NDIM;
  const short* A0 = Ahi + bofs + (size_t)blockIdx.x * 128 * NDIM;
  const short* B0 = Bhi + bofs + (size_t)blockIdx.y * 128 * NDIM;
  const short* A1 = nullptr; const short* B1 = nullptr;
  if constexpr (SPLIT){
    A1 = Alo + bofs + (size_t)blockIdx.x * 128 * NDIM;
    B1 = Blo + bofs + (size_t)blockIdx.y * 128 * NDIM;
  }

  auto stage = [&](int buf, int kt){
    #pragma unroll
    for (int i = 0; i < 2; i++){                  // 2 issues x 256 lanes x 16B = 8KB/tile
      const int grow = i * 64 + (tid >> 2);       // tile row this thread fetches
      const int slot = (tid & 3) ^ ((grow >> 1) & 3);  // pre-swizzled source k-slot
      const size_t go = (size_t)grow * NDIM + kt * 32 + slot * 8;
      const int lofs = i * 2048 + wid * 512;      // shorts; wave-uniform
      gload_lds16(A0 + go, &lds[buf][0][0] + lofs);
      gload_lds16(B0 + go, &lds[buf][TB][0] + lofs);
      if constexpr (SPLIT){
        gload_lds16(A1 + go, &lds[buf][1][0] + lofs);
        gload_lds16(B1 + go, &lds[buf][3][0] + lofs);
      }
    }
  };

  auto rfrag = [&](const short* t, int row) -> bf16x8 {
    const int p = (lane >> 4) ^ ((row >> 1) & 3);       // swizzled read
    return *(const bf16x8*)(t + row * 32 + p * 8);
  };

  f32x4 acc[4][4] = {};

  stage(0, 0);
  __syncthreads();

  for (int kt = 0; kt < 32; ++kt){
    const int cur = kt & 1;
    if (kt < 31) stage(cur ^ 1, kt + 1);

    bf16x8 ah[4], bh[4], al[4], bl[4];
    #pragma unroll
    for (int m = 0; m < 4; m++){
      const int r = wr * 64 + m * 16 + (lane & 15);
      ah[m] = rfrag(&lds[cur][0][0], r);
      if constexpr (SPLIT) al[m] = rfrag(&lds[cur][1][0], r);
    }
    #pragma unroll
    for (int n = 0; n < 4; n++){
      const int r = wc * 64 + n * 16 + (lane & 15);
      bh[n] = rfrag(&lds[cur][TB][0], r);
      if constexpr (SPLIT) bl[n] = rfrag(&lds[cur][3][0], r);
    }
    #pragma unroll
    for (int m = 0; m < 4; m++){
      #pragma unroll
      for (int n = 0; n < 4; n++){
        acc[m][n] = __builtin_amdgcn_mfma_f32_16x16x32_bf16(ah[m], bh[n], acc[m][n], 0, 0, 0);
        if constexpr (SPLIT){
          acc[m][n] = __builtin_amdgcn_mfma_f32_16x16x32_bf16(ah[m], bl[n], acc[m][n], 0, 0, 0);
          acc[m][n] = __builtin_amdgcn_mfma_f32_16x16x32_bf16(al[m], bh[n], acc[m][n], 0, 0, 0);
        }
      }
    }
    __syncthreads();
  }

  // epilogue: C/D layout col=lane&15, row=(lane>>4)*4+reg (m89)
  float* Cb = C + bofs;
  const int row0 = blockIdx.x * 128 + wr * 64 + (lane >> 4) * 4;
  const int col0 = blockIdx.y * 128 + wc * 64 + (lane & 15);
  #pragma unroll
  for (int m = 0; m < 4; m++)
    #pragma unroll
    for (int n = 0; n < 4; n++)
      #pragma unroll
      for (int r = 0; r < 4; r++)
        Cb[(size_t)(row0 + m * 16 + r) * NDIM + col0 + n * 16] = acc[m][n][r];
}

// -------- masked softmax over last dim, in-place on f32 weight; also emits bf16 weight.
// One wave per row (1024 f32). Masked (mask==0) positions -> weight 0 exactly, and are
// excluded from max/sum (identical to softmax with -1e20 fill).
__global__ __launch_bounds__(256) void k_softmax(float* __restrict__ w,
                                                 short* __restrict__ wbf,
                                                 const int* __restrict__ mask)
{
  const int gw   = blockIdx.x * 4 + (threadIdx.x >> 6);
  const int b    = gw >> 10;
  const int x    = gw & 1023;
  const int lane = threadIdx.x & 63;
  float* row  = w   + ((size_t)b * NDIM + x) * NDIM;
  short* rowb = wbf + ((size_t)b * NDIM + x) * NDIM;
  const int* mrow = mask + b * NDIM;

  f32x4 v[4]; i32x4 mk[4];
  float mx = -INFINITY;
  #pragma unroll
  for (int j = 0; j < 4; j++){
    const int c = j * 256 + lane * 4;
    v[j]  = *(const f32x4*)(row + c);
    mk[j] = *(const i32x4*)(mrow + c);
    #pragma unroll
    for (int e = 0; e < 4; e++)
      if (mk[j][e]) mx = fmaxf(mx, v[j][e]);
  }
  #pragma unroll
  for (int off = 32; off >= 1; off >>= 1) mx = fmaxf(mx, __shfl_xor(mx, off));

  float sum = 0.f;
  #pragma unroll
  for (int j = 0; j < 4; j++)
    #pragma unroll
    for (int e = 0; e < 4; e++){
      const float p = mk[j][e] ? __expf(v[j][e] - mx) : 0.f;
      v[j][e] = p; sum += p;
    }
  #pragma unroll
  for (int off = 32; off >= 1; off >>= 1) sum += __shfl_xor(sum, off);
  const float inv = sum > 0.f ? 1.f / sum : 0.f;

  #pragma unroll
  for (int j = 0; j < 4; j++){
    const int c = j * 256 + lane * 4;
    f32x4 o; short4_t ob;
    #pragma unroll
    for (int e = 0; e < 4; e++){
      const float p = v[j][e] * inv;
      o[e] = p; ob[e] = f2bf(p);
    }
    *(f32x4*)(row + c)  = o;
    *(short4_t*)(rowb + c) = ob;
  }
}

extern "C" void kernel_launch(void* const* d_in, const int* in_sizes, int n_in,
                              void* d_out, int out_size, void* d_ws, size_t ws_size,
                              hipStream_t stream)
{
  const float* xs   = (const float*)d_in[0];
  const float* ys   = (const float*)d_in[1];
  const int*   mask = (const int*)d_in[2];

  float* emb = (float*)d_out;            // [16,1024,1024] f32
  float* wgt = emb + (size_t)NEL;        // [16,1024,1024] f32

  // workspace layout (5 x NEL shorts = 168 MB)
  short* xs_hi = (short*)d_ws;
  short* xs_lo = xs_hi + NEL;
  short* ys_hi = xs_lo + NEL;
  short* ys_lo = ys_hi + NEL;
  short* ysT   = ys_lo + NEL;            // [b][d][y] bf16
  short* w_bf  = xs_hi;                  // alias: xs_hi/lo dead after GEMM1

  // 1. split-convert inputs
  k_split<<<NEL / 1024, 256, 0, stream>>>(xs, xs_hi, xs_lo);
  k_split<<<NEL / 1024, 256, 0, stream>>>(ys, ys_hi, ys_lo);
  // 2. ys transposed (bf16) for the PV GEMM
  k_transpose<<<dim3(32, 32, NBATCH), dim3(32, 8), 0, stream>>>(ys, ysT);
  // 3. scores = xs @ ys^T  (split-bf16, ~fp32 accuracy), written into the weight output slot
  k_gemm_bt<1><<<dim3(8, 8, NBATCH), 256, 0, stream>>>(xs_hi, xs_lo, ys_hi, ys_lo, wgt);
  // 4. masked softmax in-place (+ bf16 copy, overwriting xs_hi region)
  k_softmax<<<(NBATCH * NDIM) / 4, 256, 0, stream>>>(wgt, w_bf, mask);
  // 5. emb = weight @ ys  ==  weight @ (ysT)^T  (plain bf16)
  k_gemm_bt<0><<<dim3(8, 8, NBATCH), 256, 0, stream>>>(w_bf, nullptr, ysT, nullptr, emb);
}

// Round 5
// 404.945 us; speedup vs baseline: 1.1122x; 1.1122x over previous
//
#include <hip/hip_runtime.h>
#include <hip/hip_bf16.h>
#include <stdint.h>

// Problem constants: B=16, XL=YL=D=1024
#define NBATCH 16
#define NDIM   1024
#define NEL    (16u*1024u*1024u)

typedef __attribute__((ext_vector_type(8))) short bf16x8;
typedef __attribute__((ext_vector_type(4))) short short4_t;
typedef __attribute__((ext_vector_type(4))) float f32x4;
typedef __attribute__((ext_vector_type(4))) int   i32x4;

__device__ __forceinline__ short f2bf(float f){
  union { __hip_bfloat16 b; short s; } u;
  u.b = __float2bfloat16(f);   // RNE
  return u.s;
}
__device__ __forceinline__ float bf2f(short s){
  union { short s; __hip_bfloat16 b; } u;
  u.s = s;
  return __bfloat162float(u.b);
}

// -------- xs: f32 -> bf16 hi + lo
__global__ __launch_bounds__(256) void k_split(const float* __restrict__ in,
                                               short* __restrict__ hi,
                                               short* __restrict__ lo)
{
  const size_t i = ((size_t)blockIdx.x * 256 + threadIdx.x) * 4;
  f32x4 v = *(const f32x4*)(in + i);
  short4_t h, l;
  #pragma unroll
  for (int j = 0; j < 4; j++){
    short hb = f2bf(v[j]);
    h[j] = hb;
    l[j] = f2bf(v[j] - bf2f(hb));
  }
  *(short4_t*)(hi + i) = h;
  *(short4_t*)(lo + i) = l;
}

// -------- ys: one read pass -> ys_hi, ys_lo (straight) + ysT bf16 (transposed)
__global__ __launch_bounds__(512) void k_split_ysT(const float* __restrict__ ys,
                                                   short* __restrict__ hi,
                                                   short* __restrict__ lo,
                                                   short* __restrict__ ysT)
{
  __shared__ float t[64][65];
  const int b  = blockIdx.z;
  const int y0 = blockIdx.y * 64;
  const int d0 = blockIdx.x * 64;
  const int lx = threadIdx.x;          // 0..63
  const int ly = threadIdx.y;          // 0..7
  const float* src = ys + ((size_t)b * NDIM + y0) * NDIM + d0;
  short* ph = hi + ((size_t)b * NDIM + y0) * NDIM + d0;
  short* pl = lo + ((size_t)b * NDIM + y0) * NDIM + d0;
  #pragma unroll
  for (int r = ly; r < 64; r += 8){
    float v = src[(size_t)r * NDIM + lx];
    short hb = f2bf(v);
    ph[(size_t)r * NDIM + lx] = hb;
    pl[(size_t)r * NDIM + lx] = f2bf(v - bf2f(hb));
    t[r][lx] = v;
  }
  __syncthreads();
  short* pt = ysT + ((size_t)b * NDIM + d0) * NDIM + y0;
  #pragma unroll
  for (int r = ly; r < 64; r += 8)
    pt[(size_t)r * NDIM + lx] = f2bf(t[lx][r]);   // banks (lx+r)%32: 2-way, free
}

// -------- global->LDS direct copy, 16B/lane (dst wave-uniform; HW adds lane*16)
__device__ __forceinline__ void gload_lds16(const short* g, short* l){
  __builtin_amdgcn_global_load_lds((const __attribute__((address_space(1))) void*)g,
                                   (__attribute__((address_space(3))) void*)l,
                                   16, 0, 0);
}

#define MFMA_BF16(d, a, b) d = __builtin_amdgcn_mfma_f32_16x16x32_bf16(a, b, d, 0, 0, 0)

// ==================== 256x256-tile 8-wave phase-interleaved GEMM ====================
// C[b] (256x256 tile) += A (M x Kv, row-major) * B^T (N x Kv row-major), Kv = nt*32.
// Virtual-K segments of 1024: segment s uses (Asrc[s], Bsrc[s]) -> split-bf16 GEMM1 is
// expressed as a plain bf16 GEMM with Kv=3072 over pairs (hi,hi),(hi,lo),(lo,hi).
// 512 threads = 8 waves (2 row x 4 col), per-wave out 128x64 = acc[8][4] f32x4.
// LDS: 4-deep ring of K-tiles (A 256x32 + B 256x32 bf16 = 32 KB) = 128 KB.
// Per tile: 2 phases x {ds_read frags | stage 1 tensor of tile t+3 | barrier |
//   lgkmcnt(0)+sched_barrier | setprio(1) 16 MFMA setprio(0) | barrier}.
// Counted boundary vmcnt(8/4/0) once per tile (T3+T4). Stage->read swizzle: k-slot
// phys = slot ^ ((row>>1)&3)  (bank-conflict-free: measured 0 in round 2).
// WAR: stage of tile t+3 targets ring slot (t-1)&3, read in tile t-1, whose reads
// completed before tile t-1's final barrier (lgkmcnt(0) precedes each MFMA block).
// RAW: vmcnt chain retires tile t+1's 4 loads at tile t's boundary (12 in flight).
__global__ __launch_bounds__(512, 2) void k_gemm256(
    const short* __restrict__ A0, const short* __restrict__ A1, const short* __restrict__ A2,
    const short* __restrict__ B0, const short* __restrict__ B1, const short* __restrict__ B2,
    float* __restrict__ C, int nt)
{
  __shared__ __align__(16) short lds[4][2][2][4096];  // [ring][A/B][half][128*32]

  const int tid  = threadIdx.x;
  const int lane = tid & 63;
  const int wid  = tid >> 6;      // 0..7
  const int wr   = wid >> 2;      // 0..1  (row half)
  const int wcl  = wid & 3;       // 0..3  (col quarter)

  // XCD-chunked bijective swizzle: 256 blocks, 8 XCDs -> each XCD owns 2 full batches
  const int lid = blockIdx.x;
  const int swz = (lid & 7) * 32 + (lid >> 3);
  const int bz = swz >> 4, by = (swz >> 2) & 3, bx = swz & 3;

  const size_t bofs = (size_t)bz * NDIM * NDIM;
  const size_t arow = (size_t)bx * 256 * NDIM;
  const size_t brow = (size_t)by * 256 * NDIM;
  const short* Ap0 = A0 + bofs + arow; const short* Ap1 = A1 + bofs + arow;
  const short* Ap2 = A2 + bofs + arow;
  const short* Bp0 = B0 + bofs + brow; const short* Bp1 = B1 + bofs + brow;
  const short* Bp2 = B2 + bofs + brow;

  const int srow = tid >> 2;                              // staging row 0..127
  const int sslot = (tid & 3) ^ ((srow >> 1) & 3);        // pre-swizzled source k-slot

  auto stageT = [&](int kt, int sel){
    const int r = kt & 3;
    const int seg = kt >> 5;                              // 32 tiles per K-segment
    const int k0 = (kt & 31) * 32;
    const short* P = sel ? (seg == 0 ? Bp0 : (seg == 1 ? Bp1 : Bp2))
                         : (seg == 0 ? Ap0 : (seg == 1 ? Ap1 : Ap2));
    short* dbase = &lds[r][sel][0][0] + wid * 512;        // wave-uniform
    #pragma unroll
    for (int h = 0; h < 2; h++)
      gload_lds16(P + (size_t)(h * 128 + srow) * NDIM + k0 + sslot * 8,
                  dbase + h * 4096);
  };

  auto rdA = [&](int kt, int m) -> bf16x8 {
    const int rl = m * 16 + (lane & 15);
    const int p  = (lane >> 4) ^ ((rl >> 1) & 3);
    return *(const bf16x8*)(&lds[kt & 3][0][wr][0] + rl * 32 + p * 8);
  };
  auto rdB = [&](int kt, int n) -> bf16x8 {
    const int rb = wcl * 64 + n * 16 + (lane & 15);
    const int p  = (lane >> 4) ^ ((rb >> 1) & 3);
    return *(const bf16x8*)(&lds[kt & 3][1][rb >> 7][0] + (rb & 127) * 32 + p * 8);
  };

  f32x4 acc[8][4] = {};

  // prologue: stage tiles 0,1,2 (12 loads); wait tile 0 (8 may remain outstanding)
  stageT(0, 0); stageT(0, 1);
  stageT(1, 0); stageT(1, 1);
  stageT(2, 0); stageT(2, 1);
  asm volatile("s_waitcnt vmcnt(8)" ::: "memory");
  __builtin_amdgcn_s_barrier();

  for (int t = 0; t < nt; ++t){
    // ---- phase 0: m 0..3 x n 0..3
    bf16x8 af[4], bfr[4];
    #pragma unroll
    for (int m = 0; m < 4; m++) af[m] = rdA(t, m);
    #pragma unroll
    for (int n = 0; n < 4; n++) bfr[n] = rdB(t, n);
    if (t + 3 < nt) stageT(t + 3, 0);
    __builtin_amdgcn_s_barrier();
    asm volatile("s_waitcnt lgkmcnt(0)" ::: "memory");
    __builtin_amdgcn_sched_barrier(0);
    __builtin_amdgcn_s_setprio(1);
    #pragma unroll
    for (int m = 0; m < 4; m++)
      #pragma unroll
      for (int n = 0; n < 4; n++)
        MFMA_BF16(acc[m][n], af[m], bfr[n]);
    __builtin_amdgcn_s_setprio(0);
    __builtin_amdgcn_s_barrier();

    // ---- phase 1: m 4..7 x n 0..3 (B frags reused from registers)
    bf16x8 ag[4];
    #pragma unroll
    for (int m = 0; m < 4; m++) ag[m] = rdA(t, m + 4);
    if (t + 3 < nt) stageT(t + 3, 1);
    if (t + 1 < nt){
      if (t + 3 < nt)      asm volatile("s_waitcnt vmcnt(8)" ::: "memory");
      else if (t + 2 < nt) asm volatile("s_waitcnt vmcnt(4)" ::: "memory");
      else                 asm volatile("s_waitcnt vmcnt(0)" ::: "memory");
    }
    __builtin_amdgcn_s_barrier();
    asm volatile("s_waitcnt lgkmcnt(0)" ::: "memory");
    __builtin_amdgcn_sched_barrier(0);
    __builtin_amdgcn_s_setprio(1);
    #pragma unroll
    for (int m = 0; m < 4; m++)
      #pragma unroll
      for (int n = 0; n < 4; n++)
        MFMA_BF16(acc[m + 4][n], ag[m], bfr[n]);
    __builtin_amdgcn_s_setprio(0);
    __builtin_amdgcn_s_barrier();
  }

  // epilogue: C/D layout col=lane&15, row=(lane>>4)*4+reg (m89)
  float* Cb = C + bofs;
  const int row0 = bx * 256 + wr * 128 + (lane >> 4) * 4;
  const int col0 = by * 256 + wcl * 64 + (lane & 15);
  #pragma unroll
  for (int m = 0; m < 8; m++)
    #pragma unroll
    for (int n = 0; n < 4; n++)
      #pragma unroll
      for (int r = 0; r < 4; r++)
        Cb[(size_t)(row0 + m * 16 + r) * NDIM + col0 + n * 16] = acc[m][n][r];
}

// -------- masked softmax over last dim, in-place on f32 weight; also emits bf16 copy.
__global__ __launch_bounds__(256) void k_softmax(float* __restrict__ w,
                                                 short* __restrict__ wbf,
                                                 const int* __restrict__ mask)
{
  const int gw   = blockIdx.x * 4 + (threadIdx.x >> 6);
  const int b    = gw >> 10;
  const int x    = gw & 1023;
  const int lane = threadIdx.x & 63;
  float* row  = w   + ((size_t)b * NDIM + x) * NDIM;
  short* rowb = wbf + ((size_t)b * NDIM + x) * NDIM;
  const int* mrow = mask + b * NDIM;

  f32x4 v[4]; i32x4 mk[4];
  float mx = -INFINITY;
  #pragma unroll
  for (int j = 0; j < 4; j++){
    const int c = j * 256 + lane * 4;
    v[j]  = *(const f32x4*)(row + c);
    mk[j] = *(const i32x4*)(mrow + c);
    #pragma unroll
    for (int e = 0; e < 4; e++)
      if (mk[j][e]) mx = fmaxf(mx, v[j][e]);
  }
  #pragma unroll
  for (int off = 32; off >= 1; off >>= 1) mx = fmaxf(mx, __shfl_xor(mx, off));

  float sum = 0.f;
  #pragma unroll
  for (int j = 0; j < 4; j++)
    #pragma unroll
    for (int e = 0; e < 4; e++){
      const float p = mk[j][e] ? __expf(v[j][e] - mx) : 0.f;
      v[j][e] = p; sum += p;
    }
  #pragma unroll
  for (int off = 32; off >= 1; off >>= 1) sum += __shfl_xor(sum, off);
  const float inv = sum > 0.f ? 1.f / sum : 0.f;

  #pragma unroll
  for (int j = 0; j < 4; j++){
    const int c = j * 256 + lane * 4;
    f32x4 o; short4_t ob;
    #pragma unroll
    for (int e = 0; e < 4; e++){
      const float p = v[j][e] * inv;
      o[e] = p; ob[e] = f2bf(p);
    }
    *(f32x4*)(row + c)  = o;
    *(short4_t*)(rowb + c) = ob;
  }
}

extern "C" void kernel_launch(void* const* d_in, const int* in_sizes, int n_in,
                              void* d_out, int out_size, void* d_ws, size_t ws_size,
                              hipStream_t stream)
{
  const float* xs   = (const float*)d_in[0];
  const float* ys   = (const float*)d_in[1];
  const int*   mask = (const int*)d_in[2];

  float* emb = (float*)d_out;            // [16,1024,1024] f32
  float* wgt = emb + (size_t)NEL;        // [16,1024,1024] f32

  // workspace (5 x NEL shorts = 168 MB)
  short* xs_hi = (short*)d_ws;
  short* xs_lo = xs_hi + NEL;
  short* ys_hi = xs_lo + NEL;
  short* ys_lo = ys_hi + NEL;
  short* ysT   = ys_lo + NEL;            // [b][d][y] bf16
  short* w_bf  = xs_hi;                  // alias: xs_hi/lo dead after GEMM1

  // 1. convert inputs (ys: split + transpose fused, single read pass)
  k_split<<<NEL / 1024, 256, 0, stream>>>(xs, xs_hi, xs_lo);
  k_split_ysT<<<dim3(16, 16, NBATCH), dim3(64, 8), 0, stream>>>(ys, ys_hi, ys_lo, ysT);
  // 2. scores = xs @ ys^T via virtual K=3072: hi*hi + hi*lo + lo*hi
  k_gemm256<<<256, 512, 0, stream>>>(xs_hi, xs_hi, xs_lo,
                                     ys_hi, ys_lo, ys_hi, wgt, 96);
  // 3. masked softmax in-place (+ bf16 copy into xs_hi region)
  k_softmax<<<(NBATCH * NDIM) / 4, 256, 0, stream>>>(wgt, w_bf, mask);
  // 4. emb = weight @ ys = w_bf @ ysT^T  (plain bf16, K=1024)
  k_gemm256<<<256, 512, 0, stream>>>(w_bf, w_bf, w_bf,
                                     ysT, ysT, ysT, emb, 32);
}